// Round 17
// baseline (331.422 us; speedup 1.0000x reference)
//
#include <hip/hip_runtime.h>

#define NCH    8
#define NBASIS 30
#define NXS    256
#define NF     200
#define NX     (NXS*NXS*2)      // 131072
#define NIMG   (NCH*NBASIS)     // 240
#define NFT    13               // f-tiles of 16 (13*16 = 208 >= 200)
#define CPB    4                // channels per block (stage-3)

typedef float    f32x4  __attribute__((ext_vector_type(4)));
typedef unsigned u32x4  __attribute__((ext_vector_type(4)));
typedef short    bf16x8 __attribute__((ext_vector_type(8)));

__device__ __forceinline__ int bitrev8(int v) {
    return (int)(__builtin_bitreverse32((unsigned)v) >> 24);
}

__device__ __forceinline__ unsigned short f2bf(float f) {   // RNE f32->bf16
    unsigned u = __float_as_uint(f);
    return (unsigned short)((u + 0x7FFFu + ((u >> 16) & 1u)) >> 16);
}

// ---------------------------------------------------------------------------
// Pass 1: w = (x * csm) * (-1)^(row+col); FFT along the contiguous (col) axis.
// Output bf16 (Amid).
// ---------------------------------------------------------------------------
__global__ __launch_bounds__(256) void fft_rows_kernel(
        const float* __restrict__ x, const float* __restrict__ csm,
        unsigned short* __restrict__ Amid) {
    __shared__ float ldsRe[4][256];
    __shared__ float ldsIm[4][256];
    __shared__ float twRe[128], twIm[128];

    const int tid   = threadIdx.x;
    const int slice = tid >> 6;
    const int lane  = tid & 63;
    const int blk   = blockIdx.x;       // m*64 + rowTile
    const int m     = blk >> 6;
    const int row   = ((blk & 63) << 2) + slice;
    const int c     = m / NBASIS;
    const int b     = m - c * NBASIS;

    if (tid < 128) {
        float a = (float)tid * (1.0f / 128.0f);   // theta = pi * a
        twRe[tid] =  cospif(a);
        twIm[tid] = -sinpif(a);
    }

    const float* xr = x   + ((size_t)(b * NXS + row) * NXS) * 2;
    const float* cr = csm + ((size_t)(c * NXS + row) * NXS) * 2;
    #pragma unroll
    for (int j = 0; j < 4; ++j) {
        int col = lane + 64 * j;
        float2 xv = *(const float2*)(xr + col * 2);
        float2 cv = *(const float2*)(cr + col * 2);
        float s = ((row + col) & 1) ? -1.0f : 1.0f;
        ldsRe[slice][col] = s * (xv.x * cv.x - xv.y * cv.y);
        ldsIm[slice][col] = s * (xv.x * cv.y + xv.y * cv.x);
    }
    __syncthreads();

    #pragma unroll
    for (int half = 128; half >= 1; half >>= 1) {
        #pragma unroll
        for (int qq = 0; qq < 2; ++qq) {
            int q  = lane + 64 * qq;
            int g  = q / half;
            int j  = q - g * half;
            int i0 = g * 2 * half + j;
            int i1 = i0 + half;
            float ar = ldsRe[slice][i0], ai = ldsIm[slice][i0];
            float br = ldsRe[slice][i1], bi = ldsIm[slice][i1];
            ldsRe[slice][i0] = ar + br;
            ldsIm[slice][i0] = ai + bi;
            float dr = ar - br, di = ai - bi;
            int k = j * (128 / half);
            float wr = twRe[k], wi = twIm[k];
            ldsRe[slice][i1] = dr * wr - di * wi;
            ldsIm[slice][i1] = dr * wi + di * wr;
        }
        __syncthreads();
    }

    unsigned short* outp = Amid + (size_t)m * NX + (size_t)row * NXS * 2;
    #pragma unroll
    for (int j = 0; j < 4; ++j) {
        int k  = lane + 64 * j;
        int rk = bitrev8(k);
        unsigned pack = (unsigned)f2bf(ldsRe[slice][rk])
                      | ((unsigned)f2bf(ldsIm[slice][rk]) << 16);
        *(unsigned*)(outp + k * 2) = pack;
    }
}

// ---------------------------------------------------------------------------
// Pass 2: FFT along the row axis; bf16 in (Amid), bf16 out (Abf).
// ---------------------------------------------------------------------------
#define CTILE 16
__global__ __launch_bounds__(256) void fft_cols_kernel(
        const unsigned short* __restrict__ Amid, unsigned short* __restrict__ Abf) {
    __shared__ float ldsRe[CTILE][257];
    __shared__ float ldsIm[CTILE][257];
    __shared__ float twRe[128], twIm[128];

    const int tid = threadIdx.x;
    const int blk = blockIdx.x;
    const int m   = blk >> 4;             // 16 tiles per image
    const int k0  = (blk & 15) * CTILE;

    if (tid < 128) {
        float a = (float)tid * (1.0f / 128.0f);
        twRe[tid] =  cospif(a);
        twIm[tid] = -sinpif(a);
    }

    const unsigned short* base = Amid + (size_t)m * NX;
    #pragma unroll
    for (int it = 0; it < 16; ++it) {
        int li = it * 256 + tid;
        int r  = li >> 4;
        int cc = li & 15;
        unsigned v = *(const unsigned*)(base + ((size_t)r * NXS + k0 + cc) * 2);
        ldsRe[cc][r] = __uint_as_float(v << 16);
        ldsIm[cc][r] = __uint_as_float(v & 0xFFFF0000u);
    }
    __syncthreads();

    const int slice = tid >> 6;
    const int lane  = tid & 63;

    #pragma unroll
    for (int half = 128; half >= 1; half >>= 1) {
        #pragma unroll
        for (int ci = 0; ci < 4; ++ci) {
            int col = slice * 4 + ci;
            #pragma unroll
            for (int qq = 0; qq < 2; ++qq) {
                int q  = lane + 64 * qq;
                int g  = q / half;
                int j  = q - g * half;
                int i0 = g * 2 * half + j;
                int i1 = i0 + half;
                float ar = ldsRe[col][i0], ai = ldsIm[col][i0];
                float br = ldsRe[col][i1], bi = ldsIm[col][i1];
                ldsRe[col][i0] = ar + br;
                ldsIm[col][i0] = ai + bi;
                float dr = ar - br, di = ai - bi;
                int k = j * (128 / half);
                float wr = twRe[k], wi = twIm[k];
                ldsRe[col][i1] = dr * wr - di * wi;
                ldsIm[col][i1] = dr * wi + di * wr;
            }
        }
        __syncthreads();
    }

    unsigned short* obase = Abf + (size_t)m * NX;
    #pragma unroll
    for (int it = 0; it < 16; ++it) {
        int li = it * 256 + tid;
        int ky = li >> 4;
        int cc = li & 15;
        int kx = k0 + cc;
        int rk = bitrev8(ky);
        float s = (((ky + kx) & 1) ? -1.0f : 1.0f) * (1.0f / 256.0f);
        unsigned pack = ((unsigned)f2bf(s * ldsIm[cc][rk]) << 16)
                      |  (unsigned)f2bf(s * ldsRe[cc][rk]);
        *(unsigned*)(obase + ((size_t)ky * NXS + kx) * 2) = pack;
    }
}

// ---------------------------------------------------------------------------
// VT -> fragment-ordered bf16 (k=(lane>>4)*8+j, f=lane&15, zero-padded).
// ---------------------------------------------------------------------------
__global__ __launch_bounds__(256) void vt_prep_kernel(
        const float* __restrict__ VT, unsigned short* __restrict__ VTfrag) {
    int i = blockIdx.x * 256 + threadIdx.x;
    if (i >= NFT * 512) return;
    int ft = i >> 9, r = i & 511, lane = r >> 3, j = r & 7;
    int k = (lane >> 4) * 8 + j;
    int f = ft * 16 + (lane & 15);
    unsigned short v = 0;
    if (k < NBASIS && f < NF) v = f2bf(VT[k * NF + f]);
    VTfrag[i] = v;
}

// ---------------------------------------------------------------------------
// Stage 3. R16 post-mortem: barrier removal + Y prefetch neutral -> the store
// STREAM SHAPE is the bound (each NT instr = 4 scattered 256 B segments,
// ~3.5 TB/s effective vs fills' 6.8 at >=1 KB contiguous). This version:
// block-shared ldsW[16][268]; after a raw-s_barrier rendezvous (NO vmcnt
// drain!), wave wv drains f-rows wv*4..+3 — one store instr = 64 lanes x 16 B
// = 1 KB contiguous in a single f-row (fill pattern). Raw s_barrier +
// lgkmcnt(0) + sched_barrier(0) give LDS ordering without draining the NT
// store queue (the R13 trap). ylds unions with ldsW (ylds dead after yfrag
// gather) -> 32 KB LDS, 5 blocks/CU, grid 1024 fully resident.
// ---------------------------------------------------------------------------
__global__ __launch_bounds__(256) void project_mfma_kernel(
        const unsigned short* __restrict__ Abf,    // [240][NX] bf16
        const unsigned short* __restrict__ VTfrag, // [13][64][8] bf16
        const void*           __restrict__ maskT,  // [200][NX] byte or int32
        float* __restrict__ out) {
    __shared__ __align__(16) unsigned char smem[19456];        // ylds | ldsW
    __shared__ __align__(16) unsigned short vtlds[NFT * 512];  // 13312 B

    const int tid  = threadIdx.x;
    const int wv   = tid >> 6;
    const int lane = tid & 63;
    const int ksec = lane >> 4;
    const int fr   = lane & 15;
    const int c0   = blockIdx.y * CPB;
    const int n0b  = blockIdx.x * 256;
    const int n0w  = n0b + wv * 64;

    unsigned short (*ylds)[72]  = (unsigned short (*)[72])(smem + wv * 4864);
    float          (*ldsW)[268] = (float (*)[268])smem;   // 16 x 268 f32

    // Copy VTfrag to LDS.
    {
        const u32x4* src = (const u32x4*)VTfrag;
        u32x4*       dst = (u32x4*)vtlds;
        for (int i = tid; i < NFT * 512 / 8; i += 256) dst[i] = src[i];
    }

    // Detect mask storage: bool-as-byte vs int32 (uniform, scalar loads).
    const unsigned* mwd = (const unsigned*)maskT;
    bool byteMode = false;
    #pragma unroll
    for (int i = 0; i < 32; ++i) byteMode |= (mwd[i] > 1u);

    // Bit-pack this lane's mask: bit p = ft*16 + fn*4 + r  (f = ft*16+fr,
    // n = n0w + fn*16 + ksec*4 + r). All loads happen BEFORE any store.
    unsigned mbits[7] = {0u, 0u, 0u, 0u, 0u, 0u, 0u};
    if (byteMode) {
        const unsigned char* mb = (const unsigned char*)maskT + n0w + ksec * 4;
        #pragma unroll
        for (int ft = 0; ft < NFT; ++ft) {
            const int f_l = ft * 16 + fr;
            #pragma unroll
            for (int fn = 0; fn < 4; ++fn) {
                unsigned w = (f_l < NF)
                    ? *(const unsigned*)(mb + (size_t)f_l * NX + fn * 16) : 0u;
                unsigned nib = (w | (w >> 7) | (w >> 14) | (w >> 21)) & 0xFu;
                const int p = ft * 16 + fn * 4;
                mbits[p >> 5] |= nib << (p & 31);
            }
        }
    } else {
        const int* mi = (const int*)maskT + n0w + ksec * 4;
        #pragma unroll
        for (int ft = 0; ft < NFT; ++ft) {
            const int f_l = ft * 16 + fr;
            #pragma unroll
            for (int fn = 0; fn < 4; ++fn) {
                unsigned nib = 0u;
                if (f_l < NF) {
                    u32x4 v = *(const u32x4*)(mi + (size_t)f_l * NX + fn * 16);
                    nib = (v.x ? 1u : 0u) | (v.y ? 2u : 0u)
                        | (v.z ? 4u : 0u) | (v.w ? 8u : 0u);
                }
                const int p = ft * 16 + fn * 4;
                mbits[p >> 5] |= nib << (p & 31);
            }
        }
    }

    // Prologue: load channel c0's Y strip into registers.
    u32x4 ycur[4];
    {
        const unsigned short* src = Abf + (size_t)c0 * NBASIS * NX + n0w;
        #pragma unroll
        for (int i = 0; i < 4; ++i) {
            int idx = lane + 64 * i;             // 0..255
            int row = idx >> 3, seg = idx & 7;
            ycur[i] = (u32x4)(0u, 0u, 0u, 0u);
            if (row < NBASIS)
                ycur[i] = *(const u32x4*)(src + (size_t)row * NX + seg * 8);
        }
    }

    __syncthreads();     // vtlds ready (before any NT store -> harmless drain)

    #pragma unroll 1
    for (int cc = 0; cc < CPB; ++cc) {
        const int c = c0 + cc;

        // Write staged Y regs to this wave's ylds region.
        #pragma unroll
        for (int i = 0; i < 4; ++i) {
            int idx = lane + 64 * i;
            int row = idx >> 3, seg = idx & 7;
            *(u32x4*)&ylds[row][seg * 8] = ycur[i];
        }

        // Gather A-frags: yfrag[fn][j] = Y[k=ksec*8+j][n_local=fn*16+fr].
        bf16x8 yfrag[4];
        #pragma unroll
        for (int fn = 0; fn < 4; ++fn) {
            #pragma unroll
            for (int j = 0; j < 8; ++j)
                yfrag[fn][j] = (short)ylds[ksec * 8 + j][fn * 16 + fr];
        }
        // All waves finish gathering before smem is reused as ldsW.
        asm volatile("s_waitcnt lgkmcnt(0)" ::: "memory");
        __builtin_amdgcn_sched_barrier(0);
        __builtin_amdgcn_s_barrier();            // raw: no vmcnt drain
        __builtin_amdgcn_sched_barrier(0);

        // Issue next channel's Y loads BEFORE this channel's store stream.
        if (cc + 1 < CPB) {
            const unsigned short* src = Abf + (size_t)(c + 1) * NBASIS * NX + n0w;
            #pragma unroll
            for (int i = 0; i < 4; ++i) {
                int idx = lane + 64 * i;
                int row = idx >> 3, seg = idx & 7;
                u32x4 v = (u32x4)(0u, 0u, 0u, 0u);
                if (row < NBASIS)
                    v = *(const u32x4*)(src + (size_t)row * NX + seg * 8);
                ycur[i] = v;
            }
        }

        float* outc = out + (size_t)c * NF * NX;

        #pragma unroll 1
        for (int ft = 0; ft < NFT; ++ft) {
            bf16x8 vt = *(const bf16x8*)&vtlds[ft * 512 + lane * 8];

            #pragma unroll
            for (int fn = 0; fn < 4; ++fn) {
                const int p = ft * 16 + fn * 4;
                const unsigned nib = (mbits[p >> 5] >> (p & 31)) & 0xFu;
                f32x4 d = __builtin_amdgcn_mfma_f32_16x16x32_bf16(
                    yfrag[fn], vt, (f32x4)(0.f, 0.f, 0.f, 0.f), 0, 0, 0);
                f32x4 o;
                #pragma unroll
                for (int r = 0; r < 4; ++r)
                    o[r] = (nib & (1u << r)) ? d[r] : 0.0f;
                *(f32x4*)&ldsW[fr][wv * 64 + fn * 16 + ksec * 4] = o;
            }
            // Rendezvous: all D writes in LDS, no vmcnt drain.
            asm volatile("s_waitcnt lgkmcnt(0)" ::: "memory");
            __builtin_amdgcn_sched_barrier(0);
            __builtin_amdgcn_s_barrier();
            __builtin_amdgcn_sched_barrier(0);

            // Drain: wave wv stores f-rows wv*4..wv*4+3; one instr = 64 lanes
            // x 16 B = 1 KB contiguous within one f-row.
            #pragma unroll
            for (int q = 0; q < 4; ++q) {
                int f_local = wv * 4 + q;
                int f = ft * 16 + f_local;
                f32x4 v = *(const f32x4*)&ldsW[f_local][lane * 4];
                if (f < NF)
                    __builtin_nontemporal_store(v,
                        (f32x4*)(outc + (size_t)f * NX + n0b + lane * 4));
            }
            // Reads consumed (stores issued); rendezvous before next overwrite.
            asm volatile("s_waitcnt lgkmcnt(0)" ::: "memory");
            __builtin_amdgcn_sched_barrier(0);
            __builtin_amdgcn_s_barrier();
            __builtin_amdgcn_sched_barrier(0);
        }
    }
}

extern "C" void kernel_launch(void* const* d_in, const int* in_sizes, int n_in,
                              void* d_out, int out_size, void* d_ws, size_t ws_size,
                              hipStream_t stream) {
    const float* x    = (const float*)d_in[0];   // (30,256,256,2) f32
    const float* csm  = (const float*)d_in[1];   // (8,256,256,2) f32
    const float* VT   = (const float*)d_in[2];   // (30,200) f32
    const void*  mask = d_in[3];                 // (200,131072) bool/int
    float* out = (float*)d_out;                  // (8,200,131072) f32

    char* ws = (char*)d_ws;
    unsigned short* Amid   = (unsigned short*)ws;                         // 62.9 MB
    unsigned short* Abf    = (unsigned short*)(ws + ((size_t)64 << 20));  // 62.9 MB
    unsigned short* VTfrag = (unsigned short*)(ws + ((size_t)128 << 20)); // 13.3 KB

    vt_prep_kernel<<<(NFT * 512 + 255) / 256, 256, 0, stream>>>(VT, VTfrag);
    fft_rows_kernel<<<NIMG * 64, 256, 0, stream>>>(x, csm, Amid);
    fft_cols_kernel<<<NIMG * 16, 256, 0, stream>>>(Amid, Abf);
    project_mfma_kernel<<<dim3(NX / 256, NCH / CPB), 256, 0, stream>>>(
        Abf, VTfrag, mask, out);
}